// Round 1
// baseline (834.458 us; speedup 1.0000x reference)
//
#include <hip/hip_runtime.h>
#include <hip/hip_bf16.h>

typedef __bf16 bf16x8 __attribute__((ext_vector_type(8)));
typedef float f32x4 __attribute__((ext_vector_type(4)));
typedef short s16x4 __attribute__((ext_vector_type(4)));
typedef short s16x8 __attribute__((ext_vector_type(8)));

__device__ __forceinline__ short f2bf(float f) {
  union { float f; unsigned u; } v; v.f = f;
  unsigned r = (v.u + 0x7fffu + ((v.u >> 16) & 1u)) >> 16;
  return (short)r;
}
__device__ __forceinline__ float bf2f(short s) {
  union { unsigned u; float f; } v; v.u = ((unsigned)(unsigned short)s) << 16;
  return v.f;
}

// ---------------- fp32 -> bf16 convert (vectorized, grid-stride) ----------------
__global__ void cvt_kernel(const float* __restrict__ in, short* __restrict__ out, int n4) {
  for (int i = blockIdx.x * blockDim.x + threadIdx.x; i < n4; i += gridDim.x * blockDim.x) {
    const float4 v = reinterpret_cast<const float4*>(in)[i];
    s16x4 o;
    o[0] = f2bf(v.x); o[1] = f2bf(v.y); o[2] = f2bf(v.z); o[3] = f2bf(v.w);
    reinterpret_cast<s16x4*>(out)[i] = o;
  }
}

// ---------------- RoPE in-place on bf16 [B,S,H,64], freqs fp32 [S,32] ----------------
__global__ void rope_kernel(short* __restrict__ X, const float* __restrict__ cosT,
                            const float* __restrict__ sinT, int H, int total) {
  const int i = blockIdx.x * blockDim.x + threadIdx.x;
  if (i >= total) return;
  const int p = i & 31;          // pair index within head (HEAD_DIM/2 = 32)
  const int bsh = i >> 5;
  const int h = bsh % H;
  const int bs = bsh / H;        // b*S + s
  const int s = bs & 2047;       // S = 2048
  const size_t base = ((size_t)bs * H + h) * 64 + 2 * p;
  const float c = cosT[s * 32 + p];
  const float sn = sinT[s * 32 + p];
  const float e = bf2f(X[base]);
  const float o = bf2f(X[base + 1]);
  X[base] = f2bf(e * c - o * sn);
  X[base + 1] = f2bf(e * sn + o * c);
}

// ---------------- bf16 MFMA GEMM: A[M,K] @ B[K,N], 128x128 tile ----------------
// 256 threads = 4 waves, each wave a 64x64 sub-tile (4x4 frags of 16x16x32).
// B transposed into LDS at staging so both frag loads are contiguous 16B ds_reads.
template <bool OUT_BF16>
__global__ __launch_bounds__(256) void gemm_bf16(const short* __restrict__ A,
                                                 const short* __restrict__ B,
                                                 void* __restrict__ Cv,
                                                 int M, int N, int K) {
  __shared__ short As[128][72];  // +8 pad: 2-way-max bank aliasing on b128 reads
  __shared__ short Bs[128][72];  // stored [n][k]
  const int tid = threadIdx.x;
  const int lane = tid & 63;
  const int wid = tid >> 6;
  const int row0 = blockIdx.x * 128;
  const int col0 = blockIdx.y * 128;
  const int wr = (wid >> 1) * 64;
  const int wc = (wid & 1) * 64;
  const int lr = lane & 15;
  const int lk = (lane >> 4) * 8;

  f32x4 acc[4][4] = {};

  const int ar = tid >> 3, ac = (tid & 7) * 8;
  const int bk = tid >> 5, bn = (tid & 31) * 4;

  for (int k0 = 0; k0 < K; k0 += 64) {
    #pragma unroll
    for (int p = 0; p < 4; ++p) {
      const s16x8 v = *reinterpret_cast<const s16x8*>(&A[(size_t)(row0 + ar + p * 32) * K + k0 + ac]);
      *reinterpret_cast<s16x8*>(&As[ar + p * 32][ac]) = v;
    }
    #pragma unroll
    for (int p = 0; p < 8; ++p) {
      const s16x4 v = *reinterpret_cast<const s16x4*>(&B[(size_t)(k0 + bk + p * 8) * N + col0 + bn]);
      #pragma unroll
      for (int i = 0; i < 4; ++i) Bs[bn + i][bk + p * 8] = v[i];
    }
    __syncthreads();
    #pragma unroll
    for (int kk = 0; kk < 64; kk += 32) {
      bf16x8 af[4], bfr[4];
      #pragma unroll
      for (int m = 0; m < 4; ++m)
        af[m] = *reinterpret_cast<const bf16x8*>(&As[wr + m * 16 + lr][kk + lk]);
      #pragma unroll
      for (int n = 0; n < 4; ++n)
        bfr[n] = *reinterpret_cast<const bf16x8*>(&Bs[wc + n * 16 + lr][kk + lk]);
      #pragma unroll
      for (int m = 0; m < 4; ++m)
        #pragma unroll
        for (int n = 0; n < 4; ++n)
          acc[m][n] = __builtin_amdgcn_mfma_f32_16x16x32_bf16(af[m], bfr[n], acc[m][n], 0, 0, 0);
    }
    __syncthreads();
  }
  // epilogue: C/D layout col = lane&15, row = (lane>>4)*4 + reg
  const int lc = lane & 15, lr4 = (lane >> 4) * 4;
  #pragma unroll
  for (int m = 0; m < 4; ++m) {
    #pragma unroll
    for (int n = 0; n < 4; ++n) {
      #pragma unroll
      for (int i = 0; i < 4; ++i) {
        const int row = row0 + wr + m * 16 + lr4 + i;
        const int col = col0 + wc + n * 16 + lc;
        const float val = acc[m][n][i];
        if constexpr (OUT_BF16)
          ((short*)Cv)[(size_t)row * N + col] = f2bf(val);
        else
          ((float*)Cv)[(size_t)row * N + col] = val;
      }
    }
  }
}

// ---------------- causal GQA flash attention ----------------
// Q[B,S,32,64], K/V[B,S,8,64] bf16 -> O[B,S,32,64] bf16 (= [B,S,2048] for final GEMM)
// one block = (b, h, 64 q-rows); 4 waves x 16 q-rows each; KV tile = 64.
__global__ __launch_bounds__(256) void attn_kernel(const short* __restrict__ Q,
                                                   const short* __restrict__ K,
                                                   const short* __restrict__ V,
                                                   short* __restrict__ O) {
  constexpr int S = 2048, H = 32, KVH = 8;
  const int bid = blockIdx.x;
  const int qt = bid & 31;        // S/64 = 32 q-tiles
  const int h = (bid >> 5) & 31;  // 32 heads
  const int b = bid >> 10;
  const int q0 = qt * 64;
  const int kvh = h >> 2;         // N_REP = 4
  const int tid = threadIdx.x;
  const int wid = tid >> 6;
  const int lane = tid & 63;
  const int lr = lane & 15;
  const int lk = (lane >> 4) * 8;
  const int lr4 = (lane >> 4) * 4;

  __shared__ short Ks[64][72];      // [token][d]
  __shared__ short Vt[64][72];      // [d][token] (transposed at staging)
  __shared__ short Ps[4][16][72];   // per-wave P round-trip buffer

  // hoist Q fragments (A-operand: row = lane&15, k = (lane>>4)*8)
  bf16x8 qf[2];
  {
    const size_t qbase = ((size_t)(b * S + q0 + wid * 16 + lr) * H + h) * 64;
    qf[0] = *reinterpret_cast<const bf16x8*>(&Q[qbase + lk]);
    qf[1] = *reinterpret_cast<const bf16x8*>(&Q[qbase + 32 + lk]);
  }

  f32x4 oacc[4] = {};
  float m_r[4], l_r[4];
  #pragma unroll
  for (int r = 0; r < 4; ++r) { m_r[r] = -__builtin_inff(); l_r[r] = 0.f; }

  const int njt = qt + 1;  // causal: only tiles j*64 <= q0+63
  for (int j = 0; j < njt; ++j) {
    // ---- stage K tile [64 tok][64 d] and V^T tile [64 d][64 tok] ----
    {
      const int rr = tid >> 3, cc = (tid & 7) * 8;
      #pragma unroll
      for (int p = 0; p < 2; ++p) {
        const s16x8 v = *reinterpret_cast<const s16x8*>(
            &K[((size_t)(b * S + j * 64 + rr + p * 32) * KVH + kvh) * 64 + cc]);
        *reinterpret_cast<s16x8*>(&Ks[rr + p * 32][cc]) = v;
      }
      const int vt0 = tid >> 4, vd = (tid & 15) * 4;
      #pragma unroll
      for (int p = 0; p < 4; ++p) {
        const int tok = vt0 + p * 16;
        const s16x4 v = *reinterpret_cast<const s16x4*>(
            &V[((size_t)(b * S + j * 64 + tok) * KVH + kvh) * 64 + vd]);
        #pragma unroll
        for (int i = 0; i < 4; ++i) Vt[vd + i][tok] = v[i];
      }
    }
    __syncthreads();

    // ---- S = Q K^T : B-operand col = token, k = d (contiguous in Ks rows) ----
    f32x4 sf[4];
    #pragma unroll
    for (int f = 0; f < 4; ++f) {
      const bf16x8 k0f = *reinterpret_cast<const bf16x8*>(&Ks[f * 16 + lr][lk]);
      const bf16x8 k1f = *reinterpret_cast<const bf16x8*>(&Ks[f * 16 + lr][32 + lk]);
      f32x4 z = {};
      z = __builtin_amdgcn_mfma_f32_16x16x32_bf16(qf[0], k0f, z, 0, 0, 0);
      sf[f] = __builtin_amdgcn_mfma_f32_16x16x32_bf16(qf[1], k1f, z, 0, 0, 0);
    }

    // ---- online softmax: lane holds rows lr4+r (r=0..3), cols f*16 + (lane&15) ----
    #pragma unroll
    for (int r = 0; r < 4; ++r) {
      const int q = q0 + wid * 16 + lr4 + r;
      float sv[4];
      float mx = -__builtin_inff();
      #pragma unroll
      for (int f = 0; f < 4; ++f) {
        float s = sf[f][r] * 0.125f;  // 1/sqrt(64)
        const int tok = j * 64 + f * 16 + lr;
        if (tok > q) s = -__builtin_inff();
        sv[f] = s;
        mx = fmaxf(mx, s);
      }
      #pragma unroll
      for (int d = 1; d < 16; d <<= 1) mx = fmaxf(mx, __shfl_xor(mx, d, 64));
      const float mn = fmaxf(m_r[r], mx);
      const float sc_old = __expf(m_r[r] - mn);  // exp(-inf)=0 on first tile
      float lsum = 0.f;
      #pragma unroll
      for (int f = 0; f < 4; ++f) {
        const float p = __expf(sv[f] - mn);
        lsum += p;
        Ps[wid][lr4 + r][f * 16 + lr] = f2bf(p);
      }
      #pragma unroll
      for (int d = 1; d < 16; d <<= 1) lsum += __shfl_xor(lsum, d, 64);
      l_r[r] = l_r[r] * sc_old + lsum;
      m_r[r] = mn;
      #pragma unroll
      for (int f = 0; f < 4; ++f) oacc[f][r] *= sc_old;
    }
    __syncthreads();

    // ---- O += P V : P A-operand from LDS, V^T B-operand (col = d, k = token) ----
    {
      const bf16x8 pA0 = *reinterpret_cast<const bf16x8*>(&Ps[wid][lr][lk]);
      const bf16x8 pA1 = *reinterpret_cast<const bf16x8*>(&Ps[wid][lr][32 + lk]);
      #pragma unroll
      for (int f = 0; f < 4; ++f) {
        const bf16x8 v0 = *reinterpret_cast<const bf16x8*>(&Vt[f * 16 + lr][lk]);
        const bf16x8 v1 = *reinterpret_cast<const bf16x8*>(&Vt[f * 16 + lr][32 + lk]);
        oacc[f] = __builtin_amdgcn_mfma_f32_16x16x32_bf16(pA0, v0, oacc[f], 0, 0, 0);
        oacc[f] = __builtin_amdgcn_mfma_f32_16x16x32_bf16(pA1, v1, oacc[f], 0, 0, 0);
      }
    }
    __syncthreads();
  }

  // ---- normalize + store bf16 [B,S,H*64] ----
  #pragma unroll
  for (int r = 0; r < 4; ++r) {
    const float inv = 1.f / l_r[r];
    const int q = q0 + wid * 16 + lr4 + r;
    #pragma unroll
    for (int f = 0; f < 4; ++f) {
      O[((size_t)(b * S + q) * H + h) * 64 + f * 16 + lr] = f2bf(oacc[f][r] * inv);
    }
  }
}

extern "C" void kernel_launch(void* const* d_in, const int* in_sizes, int n_in,
                              void* d_out, int out_size, void* d_ws, size_t ws_size,
                              hipStream_t stream) {
  const float* x  = (const float*)d_in[0];
  const float* fc = (const float*)d_in[1];
  const float* fs = (const float*)d_in[2];
  // d_in[3] = mask (unused; causality applied analytically)
  const float* wq = (const float*)d_in[4];
  const float* wk = (const float*)d_in[5];
  const float* wv = (const float*)d_in[6];
  const float* wo = (const float*)d_in[7];
  float* out = (float*)d_out;

  constexpr int B = 2, S = 2048, DIM = 2048;
  constexpr int M = B * S;  // 4096

  // workspace layout (bf16 as short), total ~60 MB
  short* xb  = (short*)d_ws;        // 8388608  : x bf16
  short* wqb = xb  + 8388608;       // 4194304
  short* wkb = wqb + 4194304;       // 1048576
  short* wvb = wkb + 1048576;       // 1048576
  short* wob = wvb + 1048576;       // 4194304
  short* Qb  = wob + 4194304;       // 8388608  : Q (rope'd)
  short* Kb  = Qb  + 8388608;       // 2097152  : K (rope'd)
  short* Vb  = Kb  + 2097152;       // 2097152  : V
  short* attb = xb;                 // alias: x dead after V GEMM

  // 1) fp32 -> bf16
  cvt_kernel<<<2048, 256, 0, stream>>>(x,  xb,  8388608 / 4);
  cvt_kernel<<<1024, 256, 0, stream>>>(wq, wqb, 4194304 / 4);
  cvt_kernel<<<256,  256, 0, stream>>>(wk, wkb, 1048576 / 4);
  cvt_kernel<<<256,  256, 0, stream>>>(wv, wvb, 1048576 / 4);
  cvt_kernel<<<1024, 256, 0, stream>>>(wo, wob, 4194304 / 4);

  // 2) projections
  gemm_bf16<true><<<dim3(32, 16), 256, 0, stream>>>(xb, wqb, Qb, M, 2048, DIM);
  gemm_bf16<true><<<dim3(32, 4),  256, 0, stream>>>(xb, wkb, Kb, M, 512,  DIM);
  gemm_bf16<true><<<dim3(32, 4),  256, 0, stream>>>(xb, wvb, Vb, M, 512,  DIM);

  // 3) RoPE on Q (32 heads) and K (8 heads)
  rope_kernel<<<4194304 / 256, 256, 0, stream>>>(Qb, fc, fs, 32, 4194304);
  rope_kernel<<<1048576 / 256, 256, 0, stream>>>(Kb, fc, fs, 8, 1048576);

  // 4) causal GQA flash attention: B*H*(S/64) = 2048 blocks
  attn_kernel<<<2048, 256, 0, stream>>>(Qb, Kb, Vb, attb);

  // 5) output projection, fp32 out
  gemm_bf16<false><<<dim3(32, 16), 256, 0, stream>>>(attb, wob, out, M, DIM, DIM);
}

// Round 3
// 543.156 us; speedup vs baseline: 1.5363x; 1.5363x over previous
//
#include <hip/hip_runtime.h>
#include <hip/hip_bf16.h>

typedef __bf16 bf16x8 __attribute__((ext_vector_type(8)));
typedef float f32x4 __attribute__((ext_vector_type(4)));
typedef short s16x4 __attribute__((ext_vector_type(4)));
typedef short s16x8 __attribute__((ext_vector_type(8)));

__device__ __forceinline__ short f2bf(float f) {
  union { float f; unsigned u; } v; v.f = f;
  unsigned r = (v.u + 0x7fffu + ((v.u >> 16) & 1u)) >> 16;
  return (short)r;
}
__device__ __forceinline__ float bf2f(short s) {
  union { unsigned u; float f; } v; v.u = ((unsigned)(unsigned short)s) << 16;
  return v.f;
}
__device__ __forceinline__ void gload16(const void* g, void* l) {
  __builtin_amdgcn_global_load_lds(
      (const __attribute__((address_space(1))) unsigned*)g,
      (__attribute__((address_space(3))) unsigned*)l, 16, 0, 0);
}

// ---------------- fp32 -> bf16 convert (vectorized, grid-stride) ----------------
__global__ void cvt_kernel(const float* __restrict__ in, short* __restrict__ out, int n4) {
  for (int i = blockIdx.x * blockDim.x + threadIdx.x; i < n4; i += gridDim.x * blockDim.x) {
    const float4 v = reinterpret_cast<const float4*>(in)[i];
    s16x4 o;
    o[0] = f2bf(v.x); o[1] = f2bf(v.y); o[2] = f2bf(v.z); o[3] = f2bf(v.w);
    reinterpret_cast<s16x4*>(out)[i] = o;
  }
}

// ------------- fp32 [K][N] -> bf16 transposed [N][K], 32x32 LDS tiles -------------
__global__ __launch_bounds__(256) void cvtT_kernel(const float* __restrict__ W,
                                                   short* __restrict__ WT, int K, int N) {
  __shared__ float T[32][33];
  const int k0 = blockIdx.x * 32, n0 = blockIdx.y * 32;
  const int r = threadIdx.x >> 5, c = threadIdx.x & 31;
  #pragma unroll
  for (int q = 0; q < 4; ++q) T[r + q * 8][c] = W[(size_t)(k0 + r + q * 8) * N + n0 + c];
  __syncthreads();
  #pragma unroll
  for (int q = 0; q < 4; ++q) WT[(size_t)(n0 + r + q * 8) * K + k0 + c] = f2bf(T[c][r + q * 8]);
}

// ---------------- RoPE in-place, 8 elems (4 pairs) per thread ----------------
// SHIFT=8: Q layout [b,s,32,64]; SHIFT=6: K layout [b,s,8,64]
template <int SHIFT>
__global__ void rope8(short* __restrict__ X, const float* __restrict__ cosT,
                      const float* __restrict__ sinT, int n) {
  const int i = blockIdx.x * blockDim.x + threadIdx.x;
  if (i >= n) return;
  const int s = (i >> SHIFT) & 2047;
  const int p0 = (i & 7) * 4;
  s16x8 v = *reinterpret_cast<const s16x8*>(&X[(size_t)i * 8]);
  #pragma unroll
  for (int jj = 0; jj < 4; ++jj) {
    const float c = cosT[s * 32 + p0 + jj];
    const float sn = sinT[s * 32 + p0 + jj];
    const float e = bf2f(v[2 * jj]), o = bf2f(v[2 * jj + 1]);
    v[2 * jj] = f2bf(e * c - o * sn);
    v[2 * jj + 1] = f2bf(e * sn + o * c);
  }
  *reinterpret_cast<s16x8*>(&X[(size_t)i * 8]) = v;
}

// ---------------- m97-style bf16 GEMM: A[M,K] @ BT[N,K]^T, 128x128, BK=64 ----------------
// EPI: 0 = bf16 C0[M][N]; 2 = fp32 C0[M][N]
template <int EPI>
__global__ __launch_bounds__(256) void gemm_tn(const short* __restrict__ A,
                                               const short* __restrict__ BT,
                                               void* __restrict__ C0,
                                               int M, int N, int K) {
  __shared__ short As[128 * 64];
  __shared__ short Bs[128 * 64];
  const int tid = threadIdx.x, lane = tid & 63, wid = tid >> 6;
  const int row0 = blockIdx.x * 128, col0 = blockIdx.y * 128;
  const int wr = (wid >> 1) * 64, wc = (wid & 1) * 64;
  const int lr = lane & 15, lk = (lane >> 4) * 8;
  f32x4 acc[4][4] = {};

  for (int k0 = 0; k0 < K; k0 += 64) {
    #pragma unroll
    for (int i = 0; i < 4; ++i) {
      const int c = i * 256 + tid, r = c >> 3, ch = (c & 7) * 8;
      gload16(&A[(size_t)(row0 + r) * K + k0 + ch], &As[r * 64 + ch]);
      gload16(&BT[(size_t)(col0 + r) * K + k0 + ch], &Bs[r * 64 + ch]);
    }
    __syncthreads();
    #pragma unroll
    for (int kk = 0; kk < 64; kk += 32) {
      bf16x8 af[4], bfr[4];
      #pragma unroll
      for (int m = 0; m < 4; ++m)
        af[m] = *reinterpret_cast<const bf16x8*>(&As[(wr + m * 16 + lr) * 64 + kk + lk]);
      #pragma unroll
      for (int n = 0; n < 4; ++n)
        bfr[n] = *reinterpret_cast<const bf16x8*>(&Bs[(wc + n * 16 + lr) * 64 + kk + lk]);
      #pragma unroll
      for (int m = 0; m < 4; ++m)
        #pragma unroll
        for (int n = 0; n < 4; ++n)
          acc[m][n] = __builtin_amdgcn_mfma_f32_16x16x32_bf16(af[m], bfr[n], acc[m][n], 0, 0, 0);
    }
    __syncthreads();
  }

  const int lc = lane & 15, lr4 = (lane >> 4) * 4;
  #pragma unroll
  for (int m = 0; m < 4; ++m)
    #pragma unroll
    for (int n = 0; n < 4; ++n)
      #pragma unroll
      for (int i = 0; i < 4; ++i) {
        const int row = row0 + wr + m * 16 + lr4 + i;
        const int col = col0 + wc + n * 16 + lc;
        if constexpr (EPI == 0) ((short*)C0)[(size_t)row * N + col] = f2bf(acc[m][n][i]);
        else                    ((float*)C0)[(size_t)row * N + col] = acc[m][n][i];
      }
}

// ---------------- causal GQA flash attention (R0-verified version, verbatim) ----------------
// Q[B,S,32,64], K/V[B,S,8,64] bf16 -> O[B,S,32,64] bf16
__global__ __launch_bounds__(256) void attn_kernel(const short* __restrict__ Q,
                                                   const short* __restrict__ K,
                                                   const short* __restrict__ V,
                                                   short* __restrict__ O) {
  constexpr int S = 2048, H = 32, KVH = 8;
  const int bid = blockIdx.x;
  const int qt = bid & 31;
  const int h = (bid >> 5) & 31;
  const int b = bid >> 10;
  const int q0 = qt * 64;
  const int kvh = h >> 2;
  const int tid = threadIdx.x;
  const int wid = tid >> 6;
  const int lane = tid & 63;
  const int lr = lane & 15;
  const int lk = (lane >> 4) * 8;
  const int lr4 = (lane >> 4) * 4;

  __shared__ short Ks[64][72];
  __shared__ short Vt[64][72];
  __shared__ short Ps[4][16][72];

  bf16x8 qf[2];
  {
    const size_t qbase = ((size_t)(b * S + q0 + wid * 16 + lr) * H + h) * 64;
    qf[0] = *reinterpret_cast<const bf16x8*>(&Q[qbase + lk]);
    qf[1] = *reinterpret_cast<const bf16x8*>(&Q[qbase + 32 + lk]);
  }

  f32x4 oacc[4] = {};
  float m_r[4], l_r[4];
  #pragma unroll
  for (int r = 0; r < 4; ++r) { m_r[r] = -__builtin_inff(); l_r[r] = 0.f; }

  const int njt = qt + 1;
  for (int j = 0; j < njt; ++j) {
    {
      const int rr = tid >> 3, cc = (tid & 7) * 8;
      #pragma unroll
      for (int p = 0; p < 2; ++p) {
        const s16x8 v = *reinterpret_cast<const s16x8*>(
            &K[((size_t)(b * S + j * 64 + rr + p * 32) * KVH + kvh) * 64 + cc]);
        *reinterpret_cast<s16x8*>(&Ks[rr + p * 32][cc]) = v;
      }
      const int vt0 = tid >> 4, vd = (tid & 15) * 4;
      #pragma unroll
      for (int p = 0; p < 4; ++p) {
        const int tok = vt0 + p * 16;
        const s16x4 v = *reinterpret_cast<const s16x4*>(
            &V[((size_t)(b * S + j * 64 + tok) * KVH + kvh) * 64 + vd]);
        #pragma unroll
        for (int i = 0; i < 4; ++i) Vt[vd + i][tok] = v[i];
      }
    }
    __syncthreads();

    f32x4 sf[4];
    #pragma unroll
    for (int f = 0; f < 4; ++f) {
      const bf16x8 k0f = *reinterpret_cast<const bf16x8*>(&Ks[f * 16 + lr][lk]);
      const bf16x8 k1f = *reinterpret_cast<const bf16x8*>(&Ks[f * 16 + lr][32 + lk]);
      f32x4 z = {};
      z = __builtin_amdgcn_mfma_f32_16x16x32_bf16(qf[0], k0f, z, 0, 0, 0);
      sf[f] = __builtin_amdgcn_mfma_f32_16x16x32_bf16(qf[1], k1f, z, 0, 0, 0);
    }

    #pragma unroll
    for (int r = 0; r < 4; ++r) {
      const int q = q0 + wid * 16 + lr4 + r;
      float sv[4];
      float mx = -__builtin_inff();
      #pragma unroll
      for (int f = 0; f < 4; ++f) {
        float s = sf[f][r] * 0.125f;
        const int tok = j * 64 + f * 16 + lr;
        if (tok > q) s = -__builtin_inff();
        sv[f] = s;
        mx = fmaxf(mx, s);
      }
      #pragma unroll
      for (int d = 1; d < 16; d <<= 1) mx = fmaxf(mx, __shfl_xor(mx, d, 64));
      const float mn = fmaxf(m_r[r], mx);
      const float sc_old = __expf(m_r[r] - mn);
      float lsum = 0.f;
      #pragma unroll
      for (int f = 0; f < 4; ++f) {
        const float p = __expf(sv[f] - mn);
        lsum += p;
        Ps[wid][lr4 + r][f * 16 + lr] = f2bf(p);
      }
      #pragma unroll
      for (int d = 1; d < 16; d <<= 1) lsum += __shfl_xor(lsum, d, 64);
      l_r[r] = l_r[r] * sc_old + lsum;
      m_r[r] = mn;
      #pragma unroll
      for (int f = 0; f < 4; ++f) oacc[f][r] *= sc_old;
    }
    __syncthreads();

    {
      const bf16x8 pA0 = *reinterpret_cast<const bf16x8*>(&Ps[wid][lr][lk]);
      const bf16x8 pA1 = *reinterpret_cast<const bf16x8*>(&Ps[wid][lr][32 + lk]);
      #pragma unroll
      for (int f = 0; f < 4; ++f) {
        const bf16x8 v0 = *reinterpret_cast<const bf16x8*>(&Vt[f * 16 + lr][lk]);
        const bf16x8 v1 = *reinterpret_cast<const bf16x8*>(&Vt[f * 16 + lr][32 + lk]);
        oacc[f] = __builtin_amdgcn_mfma_f32_16x16x32_bf16(pA0, v0, oacc[f], 0, 0, 0);
        oacc[f] = __builtin_amdgcn_mfma_f32_16x16x32_bf16(pA1, v1, oacc[f], 0, 0, 0);
      }
    }
    __syncthreads();
  }

  #pragma unroll
  for (int r = 0; r < 4; ++r) {
    const float inv = 1.f / l_r[r];
    const int q = q0 + wid * 16 + lr4 + r;
    #pragma unroll
    for (int f = 0; f < 4; ++f) {
      O[((size_t)(b * S + q) * H + h) * 64 + f * 16 + lr] = f2bf(oacc[f][r] * inv);
    }
  }
}

extern "C" void kernel_launch(void* const* d_in, const int* in_sizes, int n_in,
                              void* d_out, int out_size, void* d_ws, size_t ws_size,
                              hipStream_t stream) {
  const float* x  = (const float*)d_in[0];
  const float* fc = (const float*)d_in[1];
  const float* fs = (const float*)d_in[2];
  // d_in[3] = mask (unused; causality applied analytically)
  const float* wq = (const float*)d_in[4];
  const float* wk = (const float*)d_in[5];
  const float* wv = (const float*)d_in[6];
  const float* wo = (const float*)d_in[7];
  float* out = (float*)d_out;

  // workspace layout (bf16 as short), ~60 MB
  short* xb  = (short*)d_ws;       // [4096][2048]
  short* wqT = xb  + 8388608;      // [2048][2048]
  short* wkT = wqT + 4194304;      // [512][2048]
  short* wvT = wkT + 1048576;      // [512][2048]
  short* woT = wvT + 1048576;      // [2048][2048]
  short* Qb  = woT + 4194304;      // [b,s,32,64]
  short* Kb  = Qb  + 8388608;      // [b,s,8,64]
  short* Vb  = Kb  + 2097152;      // [b,s,8,64]
  short* attb = xb;                // alias: x dead after V GEMM

  // 1) convert x; convert+transpose weights
  cvt_kernel<<<2048, 256, 0, stream>>>(x, xb, 2097152);
  cvtT_kernel<<<dim3(64, 64), 256, 0, stream>>>(wq, wqT, 2048, 2048);
  cvtT_kernel<<<dim3(64, 16), 256, 0, stream>>>(wk, wkT, 2048, 512);
  cvtT_kernel<<<dim3(64, 16), 256, 0, stream>>>(wv, wvT, 2048, 512);
  cvtT_kernel<<<dim3(64, 64), 256, 0, stream>>>(wo, woT, 2048, 2048);

  // 2) projections (m97-pattern GEMMs, plain row-major outputs)
  gemm_tn<0><<<dim3(32, 16), 256, 0, stream>>>(xb, wqT, Qb, 4096, 2048, 2048);
  gemm_tn<0><<<dim3(32, 4),  256, 0, stream>>>(xb, wkT, Kb, 4096, 512,  2048);
  gemm_tn<0><<<dim3(32, 4),  256, 0, stream>>>(xb, wvT, Vb, 4096, 512,  2048);

  // 3) RoPE (Q: [b,s,32,64] -> SHIFT=8; K: [b,s,8,64] -> SHIFT=6)
  rope8<8><<<4096, 256, 0, stream>>>(Qb, fc, fs, 1048576);
  rope8<6><<<1024, 256, 0, stream>>>(Kb, fc, fs, 262144);

  // 4) attention (R0-verified)
  attn_kernel<<<2048, 256, 0, stream>>>(Qb, Kb, Vb, attb);

  // 5) output projection (fp32 out)
  gemm_tn<2><<<dim3(32, 16), 256, 0, stream>>>(attb, woT, out, 4096, 2048, 2048);
}

// Round 4
// 378.266 us; speedup vs baseline: 2.2060x; 1.4359x over previous
//
#include <hip/hip_runtime.h>
#include <hip/hip_bf16.h>

typedef __bf16 bf16x8 __attribute__((ext_vector_type(8)));
typedef float f32x4 __attribute__((ext_vector_type(4)));
typedef float f32x16 __attribute__((ext_vector_type(16)));
typedef short s16x4 __attribute__((ext_vector_type(4)));
typedef short s16x8 __attribute__((ext_vector_type(8)));

__device__ __forceinline__ short f2bf(float f) {
  union { float f; unsigned u; } v; v.f = f;
  unsigned r = (v.u + 0x7fffu + ((v.u >> 16) & 1u)) >> 16;
  return (short)r;
}
__device__ __forceinline__ float bf2f(short s) {
  union { unsigned u; float f; } v; v.u = ((unsigned)(unsigned short)s) << 16;
  return v.f;
}
__device__ __forceinline__ void gload16(const void* g, void* l) {
  __builtin_amdgcn_global_load_lds(
      (const __attribute__((address_space(1))) unsigned*)g,
      (__attribute__((address_space(3))) unsigned*)l, 16, 0, 0);
}
__device__ __forceinline__ unsigned pack2(float lo, float hi) {
  return ((unsigned)(unsigned short)f2bf(lo)) | (((unsigned)(unsigned short)f2bf(hi)) << 16);
}

// ---------------- fp32 -> bf16 convert (vectorized, grid-stride) ----------------
__global__ void cvt_kernel(const float* __restrict__ in, short* __restrict__ out, int n4) {
  for (int i = blockIdx.x * blockDim.x + threadIdx.x; i < n4; i += gridDim.x * blockDim.x) {
    const float4 v = reinterpret_cast<const float4*>(in)[i];
    s16x4 o;
    o[0] = f2bf(v.x); o[1] = f2bf(v.y); o[2] = f2bf(v.z); o[3] = f2bf(v.w);
    reinterpret_cast<s16x4*>(out)[i] = o;
  }
}

// ------------- fp32 [K][N] -> bf16 transposed [N][K], 32x32 LDS tiles -------------
__global__ __launch_bounds__(256) void cvtT_kernel(const float* __restrict__ W,
                                                   short* __restrict__ WT, int K, int N) {
  __shared__ float T[32][33];
  const int k0 = blockIdx.x * 32, n0 = blockIdx.y * 32;
  const int r = threadIdx.x >> 5, c = threadIdx.x & 31;
  #pragma unroll
  for (int q = 0; q < 4; ++q) T[r + q * 8][c] = W[(size_t)(k0 + r + q * 8) * N + n0 + c];
  __syncthreads();
  #pragma unroll
  for (int q = 0; q < 4; ++q) WT[(size_t)(n0 + r + q * 8) * K + k0 + c] = f2bf(T[c][r + q * 8]);
}

// ------------- bf16 V [b,s,8,64] -> VT [b*8+kvh][d][s], 32x32 LDS tiles -------------
__global__ __launch_bounds__(256) void vtrans(const short* __restrict__ Vin,
                                              short* __restrict__ VT) {
  __shared__ short T[32][33];
  const int st0 = blockIdx.x * 32;
  const int d0 = blockIdx.y * 32;
  const int bk = blockIdx.z;
  const int b = bk >> 3, kvh = bk & 7;
  const int r = threadIdx.x >> 5, c = threadIdx.x & 31;
  #pragma unroll
  for (int q = 0; q < 4; ++q)
    T[r + q * 8][c] = Vin[((size_t)(b * 2048 + st0 + r + q * 8) * 8 + kvh) * 64 + d0 + c];
  __syncthreads();
  #pragma unroll
  for (int q = 0; q < 4; ++q)
    VT[((size_t)bk * 64 + d0 + r + q * 8) * 2048 + st0 + c] = T[c][r + q * 8];
}

// ---------------- RoPE in-place, 8 elems (4 pairs) per thread ----------------
// SHIFT=8: Q layout [b,s,32,64]; SHIFT=6: K layout [b,s,8,64]
template <int SHIFT>
__global__ void rope8(short* __restrict__ X, const float* __restrict__ cosT,
                      const float* __restrict__ sinT, int n) {
  const int i = blockIdx.x * blockDim.x + threadIdx.x;
  if (i >= n) return;
  const int s = (i >> SHIFT) & 2047;
  const int p0 = (i & 7) * 4;
  s16x8 v = *reinterpret_cast<const s16x8*>(&X[(size_t)i * 8]);
  #pragma unroll
  for (int jj = 0; jj < 4; ++jj) {
    const float c = cosT[s * 32 + p0 + jj];
    const float sn = sinT[s * 32 + p0 + jj];
    const float e = bf2f(v[2 * jj]), o = bf2f(v[2 * jj + 1]);
    v[2 * jj] = f2bf(e * c - o * sn);
    v[2 * jj + 1] = f2bf(e * sn + o * c);
  }
  *reinterpret_cast<s16x8*>(&X[(size_t)i * 8]) = v;
}

// ---------------- m97-style bf16 GEMM: A[M,K] @ BT[N,K]^T, 128x128, BK=64 ----------------
template <int EPI>
__global__ __launch_bounds__(256) void gemm_tn(const short* __restrict__ A,
                                               const short* __restrict__ BT,
                                               void* __restrict__ C0,
                                               int M, int N, int K) {
  __shared__ short As[128 * 64];
  __shared__ short Bs[128 * 64];
  const int tid = threadIdx.x, lane = tid & 63, wid = tid >> 6;
  const int row0 = blockIdx.x * 128, col0 = blockIdx.y * 128;
  const int wr = (wid >> 1) * 64, wc = (wid & 1) * 64;
  const int lr = lane & 15, lk = (lane >> 4) * 8;
  f32x4 acc[4][4] = {};

  for (int k0 = 0; k0 < K; k0 += 64) {
    #pragma unroll
    for (int i = 0; i < 4; ++i) {
      const int c = i * 256 + tid, r = c >> 3, ch = (c & 7) * 8;
      gload16(&A[(size_t)(row0 + r) * K + k0 + ch], &As[r * 64 + ch]);
      gload16(&BT[(size_t)(col0 + r) * K + k0 + ch], &Bs[r * 64 + ch]);
    }
    __syncthreads();
    #pragma unroll
    for (int kk = 0; kk < 64; kk += 32) {
      bf16x8 af[4], bfr[4];
      #pragma unroll
      for (int m = 0; m < 4; ++m)
        af[m] = *reinterpret_cast<const bf16x8*>(&As[(wr + m * 16 + lr) * 64 + kk + lk]);
      #pragma unroll
      for (int n = 0; n < 4; ++n)
        bfr[n] = *reinterpret_cast<const bf16x8*>(&Bs[(wc + n * 16 + lr) * 64 + kk + lk]);
      #pragma unroll
      for (int m = 0; m < 4; ++m)
        #pragma unroll
        for (int n = 0; n < 4; ++n)
          acc[m][n] = __builtin_amdgcn_mfma_f32_16x16x32_bf16(af[m], bfr[n], acc[m][n], 0, 0, 0);
    }
    __syncthreads();
  }

  const int lc = lane & 15, lr4 = (lane >> 4) * 4;
  #pragma unroll
  for (int m = 0; m < 4; ++m)
    #pragma unroll
    for (int n = 0; n < 4; ++n)
      #pragma unroll
      for (int i = 0; i < 4; ++i) {
        const int row = row0 + wr + m * 16 + lr4 + i;
        const int col = col0 + wc + n * 16 + lc;
        if constexpr (EPI == 0) ((short*)C0)[(size_t)row * N + col] = f2bf(acc[m][n][i]);
        else                    ((float*)C0)[(size_t)row * N + col] = acc[m][n][i];
      }
}

// ---------------- causal GQA flash attention, 32x32 swapped both ways ----------------
// QK^T = mfma(K, Q): lane holds P[q = lane&31][32 tokens over regs]
// PV   = mfma(VT, P): lane holds O[d over regs][q = lane&31]  -> stats stay lane-local
// Q[b,s,32,64], K[b,s,8,64], VT[b*8+kvh][d][2048] bf16 -> O[b,s,32,64] bf16
__global__ __launch_bounds__(256) void attn2(const short* __restrict__ Q,
                                             const short* __restrict__ K,
                                             const short* __restrict__ VT,
                                             short* __restrict__ O) {
  constexpr int S = 2048, H = 32;
  const int qt = blockIdx.x, h = blockIdx.y, b = blockIdx.z;
  const int tid = threadIdx.x, lane = tid & 63, wid = tid >> 6;
  const int l31 = lane & 31, hi = lane >> 5;
  const int kvh = h >> 2;
  const int bk = b * 8 + kvh;
  const int q0 = qt * 128 + wid * 32;
  const int qrow = q0 + l31;

  __shared__ short Ks[2][4096];
  __shared__ short Vs[2][4096];

  // Q fragment (used as B in QK^T): col = lane&31 = q-row, k-slot (hi,j) = d = ds*16+hi*8+j
  bf16x8 qf[4];
  {
    const size_t qbase = ((size_t)(b * S + qrow) * H + h) * 64;
    #pragma unroll
    for (int ds = 0; ds < 4; ++ds)
      qf[ds] = *reinterpret_cast<const bf16x8*>(&Q[qbase + ds * 16 + hi * 8]);
  }

  f32x16 o0 = {}, o1 = {};
  float m_r = -1e30f, l_r = 0.f;

  const int njt = 2 * qt + 2;
  const size_t kroot = ((size_t)b * S * 8 + kvh) * 64;  // &K[b][0][kvh][0], row stride 512
  const size_t vroot = (size_t)bk * 64 * S;             // &VT[bk][0][0]

  // prologue: stage tile 0 into buf 0 (linear LDS dest, XOR-pre-swizzled global src)
  #pragma unroll
  for (int i = 0; i < 2; ++i) {
    const int c = i * 256 + tid, r = c >> 3, ch = c & 7;
    const int cs8 = (ch ^ (r & 7)) * 8;
    gload16(&K[kroot + (size_t)r * 512 + cs8], &Ks[0][c * 8]);
    gload16(&VT[vroot + (size_t)r * S + cs8], &Vs[0][c * 8]);
  }
  __syncthreads();

  int cur = 0;
  for (int j = 0; j < njt; ++j) {
    if (j + 1 < njt) {  // prefetch next tile; drained by the barrier below
      #pragma unroll
      for (int i = 0; i < 2; ++i) {
        const int c = i * 256 + tid, r = c >> 3, ch = c & 7;
        const int cs8 = (ch ^ (r & 7)) * 8;
        gload16(&K[kroot + (size_t)((j + 1) * 64 + r) * 512 + cs8], &Ks[cur ^ 1][c * 8]);
        gload16(&VT[vroot + (size_t)r * S + (j + 1) * 64 + cs8], &Vs[cur ^ 1][c * 8]);
      }
    }
    const int kb = j * 64;
    if (kb <= q0 + 31) {  // wave-uniform causal skip
      // ---- QK^T: A = K rows (tokens), B = Q. D[token][q], lane: q=l31, tok=crow(r,hi) ----
      f32x16 sa0 = {}, sa1 = {};
      #pragma unroll
      for (int ds = 0; ds < 4; ++ds) {
        const int c0 = ((ds * 2 + hi) ^ (l31 & 7)) * 8;
        const bf16x8 kf0 = *reinterpret_cast<const bf16x8*>(&Ks[cur][l31 * 64 + c0]);
        const bf16x8 kf1 = *reinterpret_cast<const bf16x8*>(&Ks[cur][(32 + l31) * 64 + c0]);
        sa0 = __builtin_amdgcn_mfma_f32_32x32x16_bf16(kf0, qf[ds], sa0, 0, 0, 0);
        sa1 = __builtin_amdgcn_mfma_f32_32x32x16_bf16(kf1, qf[ds], sa1, 0, 0, 0);
      }
      // ---- online softmax for row q = qrow (lane-local stats) ----
      float mx = -1e30f;
      #pragma unroll
      for (int r = 0; r < 16; ++r) {
        const int kk = kb + (r & 3) + 8 * (r >> 2) + 4 * hi;
        float s0 = sa0[r] * 0.125f; if (kk > qrow) s0 = -1e30f;
        float s1 = sa1[r] * 0.125f; if (kk + 32 > qrow) s1 = -1e30f;
        sa0[r] = s0; sa1[r] = s1;
        mx = fmaxf(mx, fmaxf(s0, s1));
      }
      mx = fmaxf(mx, __shfl_xor(mx, 32, 64));
      const float mn = fmaxf(m_r, mx);
      const float sc = __expf(m_r - mn);
      float ls = 0.f;
      #pragma unroll
      for (int r = 0; r < 16; ++r) {
        const float e0 = __expf(sa0[r] - mn);
        const float e1 = __expf(sa1[r] - mn);
        sa0[r] = e0; sa1[r] = e1; ls += e0 + e1;
      }
      ls += __shfl_xor(ls, 32, 64);
      l_r = l_r * sc + ls; m_r = mn;
      #pragma unroll
      for (int r = 0; r < 16; ++r) { o0[r] *= sc; o1[r] *= sc; }
      // ---- P -> B-fragments, register order (slot (hi,j) = token crow(ks*8+j, hi)) ----
      bf16x8 paf[4];
      #pragma unroll
      for (int ks = 0; ks < 4; ++ks) {
        union { unsigned w[4]; bf16x8 v; } u;
        #pragma unroll
        for (int w2 = 0; w2 < 4; ++w2) {
          const int rbase = (ks & 1) * 8 + w2 * 2;
          if (ks < 2) u.w[w2] = pack2(sa0[rbase], sa0[rbase + 1]);
          else        u.w[w2] = pack2(sa1[rbase], sa1[rbase + 1]);
        }
        paf[ks] = u.v;
      }
      // ---- PV = mfma(VT_frag, P): A slot (hi,j) = same token order via paired b64 ----
      #pragma unroll
      for (int ks = 0; ks < 4; ++ks) {
        const int g0 = ((2 * ks) ^ (l31 & 7)) * 8 + hi * 4;
        const int g1 = ((2 * ks + 1) ^ (l31 & 7)) * 8 + hi * 4;
        union { s16x4 h[2]; bf16x8 v; } a0, a1;
        a0.h[0] = *reinterpret_cast<const s16x4*>(&Vs[cur][l31 * 64 + g0]);
        a0.h[1] = *reinterpret_cast<const s16x4*>(&Vs[cur][l31 * 64 + g1]);
        a1.h[0] = *reinterpret_cast<const s16x4*>(&Vs[cur][(32 + l31) * 64 + g0]);
        a1.h[1] = *reinterpret_cast<const s16x4*>(&Vs[cur][(32 + l31) * 64 + g1]);
        o0 = __builtin_amdgcn_mfma_f32_32x32x16_bf16(a0.v, paf[ks], o0, 0, 0, 0);
        o1 = __builtin_amdgcn_mfma_f32_32x32x16_bf16(a1.v, paf[ks], o1, 0, 0, 0);
      }
    }
    __syncthreads();
    cur ^= 1;
  }

  // ---- normalize + store: o0[r] = O[d = crow(r,hi)][q = qrow], o1 at d+32 ----
  const float inv = 1.f / l_r;
  const size_t obase = ((size_t)(b * S + qrow) * H + h) * 64;
  #pragma unroll
  for (int g = 0; g < 4; ++g) {
    s16x4 s0v, s1v;
    #pragma unroll
    for (int i = 0; i < 4; ++i) {
      s0v[i] = f2bf(o0[4 * g + i] * inv);
      s1v[i] = f2bf(o1[4 * g + i] * inv);
    }
    *reinterpret_cast<s16x4*>(&O[obase + 8 * g + 4 * hi]) = s0v;
    *reinterpret_cast<s16x4*>(&O[obase + 32 + 8 * g + 4 * hi]) = s1v;
  }
}

extern "C" void kernel_launch(void* const* d_in, const int* in_sizes, int n_in,
                              void* d_out, int out_size, void* d_ws, size_t ws_size,
                              hipStream_t stream) {
  const float* x  = (const float*)d_in[0];
  const float* fc = (const float*)d_in[1];
  const float* fs = (const float*)d_in[2];
  // d_in[3] = mask (unused; causality applied analytically)
  const float* wq = (const float*)d_in[4];
  const float* wk = (const float*)d_in[5];
  const float* wv = (const float*)d_in[6];
  const float* wo = (const float*)d_in[7];
  float* out = (float*)d_out;

  // workspace layout (bf16 as short), ~60 MB
  short* xb  = (short*)d_ws;       // [4096][2048]
  short* wqT = xb  + 8388608;      // [2048][2048]
  short* wkT = wqT + 4194304;      // [512][2048]
  short* wvT = wkT + 1048576;      // [512][2048]
  short* woT = wvT + 1048576;      // [2048][2048]
  short* Qb  = woT + 4194304;      // [b,s,32,64]
  short* Kb  = Qb  + 8388608;      // [b,s,8,64]
  short* Vb  = Kb  + 2097152;      // [b,s,8,64]
  short* attb = xb;                // alias: x dead after V GEMM
  short* VTb  = wqT;               // alias: wqT dead after Q GEMM; [bk][64][2048]

  // 1) convert x; convert+transpose weights
  cvt_kernel<<<2048, 256, 0, stream>>>(x, xb, 2097152);
  cvtT_kernel<<<dim3(64, 64), 256, 0, stream>>>(wq, wqT, 2048, 2048);
  cvtT_kernel<<<dim3(64, 16), 256, 0, stream>>>(wk, wkT, 2048, 512);
  cvtT_kernel<<<dim3(64, 16), 256, 0, stream>>>(wv, wvT, 2048, 512);
  cvtT_kernel<<<dim3(64, 64), 256, 0, stream>>>(wo, woT, 2048, 2048);

  // 2) projections
  gemm_tn<0><<<dim3(32, 16), 256, 0, stream>>>(xb, wqT, Qb, 4096, 2048, 2048);
  gemm_tn<0><<<dim3(32, 4),  256, 0, stream>>>(xb, wkT, Kb, 4096, 512,  2048);
  gemm_tn<0><<<dim3(32, 4),  256, 0, stream>>>(xb, wvT, Vb, 4096, 512,  2048);

  // 3) RoPE
  rope8<8><<<4096, 256, 0, stream>>>(Qb, fc, fs, 1048576);
  rope8<6><<<1024, 256, 0, stream>>>(Kb, fc, fs, 262144);

  // 4) V transpose to [bk][d][s] (into dead wqT region)
  vtrans<<<dim3(64, 2, 16), 256, 0, stream>>>(Vb, VTb);

  // 5) attention
  attn2<<<dim3(16, 32, 2), 256, 0, stream>>>(Qb, Kb, VTb, attb);

  // 6) output projection (fp32 out)
  gemm_tn<1><<<dim3(32, 16), 256, 0, stream>>>(attb, woT, out, 4096, 2048, 2048);
}

// Round 5
// 375.497 us; speedup vs baseline: 2.2223x; 1.0074x over previous
//
#include <hip/hip_runtime.h>
#include <hip/hip_bf16.h>

typedef __bf16 bf16x8 __attribute__((ext_vector_type(8)));
typedef float f32x4 __attribute__((ext_vector_type(4)));
typedef float f32x16 __attribute__((ext_vector_type(16)));
typedef short s16x4 __attribute__((ext_vector_type(4)));
typedef short s16x8 __attribute__((ext_vector_type(8)));

__device__ __forceinline__ short f2bf(float f) {
  union { __bf16 h; short s; } p; p.h = (__bf16)f; return p.s;
}
__device__ __forceinline__ float bf2f(short s) {
  union { unsigned u; float f; } v; v.u = ((unsigned)(unsigned short)s) << 16;
  return v.f;
}
__device__ __forceinline__ void gload16(const void* g, void* l) {
  __builtin_amdgcn_global_load_lds(
      (const __attribute__((address_space(1))) unsigned*)g,
      (__attribute__((address_space(3))) unsigned*)l, 16, 0, 0);
}
__device__ __forceinline__ unsigned pack2(float lo, float hi) {
  union { __bf16 h[2]; unsigned u; } p;
  p.h[0] = (__bf16)lo; p.h[1] = (__bf16)hi;   // compiler emits v_cvt_pk_bf16_f32 (m240)
  return p.u;
}

// ---------------- fp32 -> bf16 convert (vectorized, grid-stride) ----------------
__global__ void cvt_kernel(const float* __restrict__ in, short* __restrict__ out, int n4) {
  for (int i = blockIdx.x * blockDim.x + threadIdx.x; i < n4; i += gridDim.x * blockDim.x) {
    const float4 v = reinterpret_cast<const float4*>(in)[i];
    s16x4 o;
    o[0] = f2bf(v.x); o[1] = f2bf(v.y); o[2] = f2bf(v.z); o[3] = f2bf(v.w);
    reinterpret_cast<s16x4*>(out)[i] = o;
  }
}

// ------------- fp32 [K][N] -> bf16 transposed [N][K], 32x32 LDS tiles -------------
__global__ __launch_bounds__(256) void cvtT_kernel(const float* __restrict__ W,
                                                   short* __restrict__ WT, int K, int N) {
  __shared__ float T[32][33];
  const int k0 = blockIdx.x * 32, n0 = blockIdx.y * 32;
  const int r = threadIdx.x >> 5, c = threadIdx.x & 31;
  #pragma unroll
  for (int q = 0; q < 4; ++q) T[r + q * 8][c] = W[(size_t)(k0 + r + q * 8) * N + n0 + c];
  __syncthreads();
  #pragma unroll
  for (int q = 0; q < 4; ++q) WT[(size_t)(n0 + r + q * 8) * K + k0 + c] = f2bf(T[c][r + q * 8]);
}

// ------------- bf16 V [b,s,8,64] -> VT [b*8+kvh][d][s], 32x32 LDS tiles -------------
__global__ __launch_bounds__(256) void vtrans(const short* __restrict__ Vin,
                                              short* __restrict__ VT) {
  __shared__ short T[32][33];
  const int st0 = blockIdx.x * 32;
  const int d0 = blockIdx.y * 32;
  const int bk = blockIdx.z;
  const int b = bk >> 3, kvh = bk & 7;
  const int r = threadIdx.x >> 5, c = threadIdx.x & 31;
  #pragma unroll
  for (int q = 0; q < 4; ++q)
    T[r + q * 8][c] = Vin[((size_t)(b * 2048 + st0 + r + q * 8) * 8 + kvh) * 64 + d0 + c];
  __syncthreads();
  #pragma unroll
  for (int q = 0; q < 4; ++q)
    VT[((size_t)bk * 64 + d0 + r + q * 8) * 2048 + st0 + c] = T[c][r + q * 8];
}

// ---------------- RoPE in-place, 8 elems (4 pairs) per thread ----------------
template <int SHIFT>
__global__ void rope8(short* __restrict__ X, const float* __restrict__ cosT,
                      const float* __restrict__ sinT, int n) {
  const int i = blockIdx.x * blockDim.x + threadIdx.x;
  if (i >= n) return;
  const int s = (i >> SHIFT) & 2047;
  const int p0 = (i & 7) * 4;
  s16x8 v = *reinterpret_cast<const s16x8*>(&X[(size_t)i * 8]);
  #pragma unroll
  for (int jj = 0; jj < 4; ++jj) {
    const float c = cosT[s * 32 + p0 + jj];
    const float sn = sinT[s * 32 + p0 + jj];
    const float e = bf2f(v[2 * jj]), o = bf2f(v[2 * jj + 1]);
    v[2 * jj] = f2bf(e * c - o * sn);
    v[2 * jj + 1] = f2bf(e * sn + o * c);
  }
  *reinterpret_cast<s16x8*>(&X[(size_t)i * 8]) = v;
}

// ---------------- m97-style bf16 GEMM: A[M,K] @ BT[N,K]^T, 128x128, BK=64 ----------------
template <int EPI>
__global__ __launch_bounds__(256) void gemm_tn(const short* __restrict__ A,
                                               const short* __restrict__ BT,
                                               void* __restrict__ C0,
                                               int M, int N, int K) {
  __shared__ short As[128 * 64];
  __shared__ short Bs[128 * 64];
  const int tid = threadIdx.x, lane = tid & 63, wid = tid >> 6;
  const int row0 = blockIdx.x * 128, col0 = blockIdx.y * 128;
  const int wr = (wid >> 1) * 64, wc = (wid & 1) * 64;
  const int lr = lane & 15, lk = (lane >> 4) * 8;
  f32x4 acc[4][4] = {};

  for (int k0 = 0; k0 < K; k0 += 64) {
    #pragma unroll
    for (int i = 0; i < 4; ++i) {
      const int c = i * 256 + tid, r = c >> 3, ch = (c & 7) * 8;
      gload16(&A[(size_t)(row0 + r) * K + k0 + ch], &As[r * 64 + ch]);
      gload16(&BT[(size_t)(col0 + r) * K + k0 + ch], &Bs[r * 64 + ch]);
    }
    __syncthreads();
    #pragma unroll
    for (int kk = 0; kk < 64; kk += 32) {
      bf16x8 af[4], bfr[4];
      #pragma unroll
      for (int m = 0; m < 4; ++m)
        af[m] = *reinterpret_cast<const bf16x8*>(&As[(wr + m * 16 + lr) * 64 + kk + lk]);
      #pragma unroll
      for (int n = 0; n < 4; ++n)
        bfr[n] = *reinterpret_cast<const bf16x8*>(&Bs[(wc + n * 16 + lr) * 64 + kk + lk]);
      #pragma unroll
      for (int m = 0; m < 4; ++m)
        #pragma unroll
        for (int n = 0; n < 4; ++n)
          acc[m][n] = __builtin_amdgcn_mfma_f32_16x16x32_bf16(af[m], bfr[n], acc[m][n], 0, 0, 0);
    }
    __syncthreads();
  }

  const int lc = lane & 15, lr4 = (lane >> 4) * 4;
  #pragma unroll
  for (int m = 0; m < 4; ++m)
    #pragma unroll
    for (int n = 0; n < 4; ++n)
      #pragma unroll
      for (int i = 0; i < 4; ++i) {
        const int row = row0 + wr + m * 16 + lr4 + i;
        const int col = col0 + wc + n * 16 + lc;
        if constexpr (EPI == 0) ((short*)C0)[(size_t)row * N + col] = f2bf(acc[m][n][i]);
        else                    ((float*)C0)[(size_t)row * N + col] = acc[m][n][i];
      }
}

// ---------------- causal GQA flash attention, paired q-strips ----------------
// QK^T = mfma(K, Q): lane holds P[q = lane&31][32 tokens over regs]
// PV   = mfma(VT, P): lane holds O[d over regs][q = lane&31]  -> stats lane-local
// scores pre-scaled to log2 domain (0.125 * log2e); exp2 throughout.
constexpr float KSC = 0.18033688f;  // 1/sqrt(64) * log2(e)

template <bool MASKED>
__device__ __forceinline__ void ptile(const short* __restrict__ Ksb,
                                      const short* __restrict__ Vsb,
                                      const bf16x8 qf[4], int kb, int qrow,
                                      int l31, int hi,
                                      f32x16& o0, f32x16& o1, float& m_r, float& l_r) {
  f32x16 sa0 = {}, sa1 = {};
  __builtin_amdgcn_s_setprio(1);
  #pragma unroll
  for (int ds = 0; ds < 4; ++ds) {
    const int c0 = ((ds * 2 + hi) ^ (l31 & 7)) * 8;
    const bf16x8 kf0 = *reinterpret_cast<const bf16x8*>(&Ksb[l31 * 64 + c0]);
    const bf16x8 kf1 = *reinterpret_cast<const bf16x8*>(&Ksb[(32 + l31) * 64 + c0]);
    sa0 = __builtin_amdgcn_mfma_f32_32x32x16_bf16(kf0, qf[ds], sa0, 0, 0, 0);
    sa1 = __builtin_amdgcn_mfma_f32_32x32x16_bf16(kf1, qf[ds], sa1, 0, 0, 0);
  }
  __builtin_amdgcn_s_setprio(0);
  float mx = -1e30f;
  #pragma unroll
  for (int r = 0; r < 16; ++r) {
    float s0 = sa0[r] * KSC;
    float s1 = sa1[r] * KSC;
    if (MASKED) {
      const int kk = kb + (r & 3) + 8 * (r >> 2) + 4 * hi;
      if (kk > qrow) s0 = -1e30f;
      if (kk + 32 > qrow) s1 = -1e30f;
    }
    sa0[r] = s0; sa1[r] = s1;
    mx = fmaxf(mx, fmaxf(s0, s1));
  }
  mx = fmaxf(mx, __shfl_xor(mx, 32, 64));
  // defer-max (T13): skip rescale when max growth <= 8 (log2 domain) on all lanes
  if (!__all(mx <= m_r + 8.0f)) {
    const float mn = fmaxf(m_r, mx);
    const float sc = exp2f(m_r - mn);
    #pragma unroll
    for (int r = 0; r < 16; ++r) { o0[r] *= sc; o1[r] *= sc; }
    l_r *= sc;
    m_r = mn;
  }
  float ls = 0.f;
  #pragma unroll
  for (int r = 0; r < 16; ++r) {
    const float e0 = exp2f(sa0[r] - m_r);
    const float e1 = exp2f(sa1[r] - m_r);
    sa0[r] = e0; sa1[r] = e1; ls += e0 + e1;
  }
  ls += __shfl_xor(ls, 32, 64);
  l_r += ls;
  // P -> B-fragments, register order (verified R4)
  bf16x8 paf[4];
  #pragma unroll
  for (int ks = 0; ks < 4; ++ks) {
    union { unsigned w[4]; bf16x8 v; } u;
    #pragma unroll
    for (int w2 = 0; w2 < 4; ++w2) {
      const int rbase = (ks & 1) * 8 + w2 * 2;
      if (ks < 2) u.w[w2] = pack2(sa0[rbase], sa0[rbase + 1]);
      else        u.w[w2] = pack2(sa1[rbase], sa1[rbase + 1]);
    }
    paf[ks] = u.v;
  }
  // PV = mfma(VT_frag, P) (verified R4)
  __builtin_amdgcn_s_setprio(1);
  #pragma unroll
  for (int ks = 0; ks < 4; ++ks) {
    const int g0 = ((2 * ks) ^ (l31 & 7)) * 8 + hi * 4;
    const int g1 = ((2 * ks + 1) ^ (l31 & 7)) * 8 + hi * 4;
    union { s16x4 h[2]; bf16x8 v; } a0, a1;
    a0.h[0] = *reinterpret_cast<const s16x4*>(&Vsb[l31 * 64 + g0]);
    a0.h[1] = *reinterpret_cast<const s16x4*>(&Vsb[l31 * 64 + g1]);
    a1.h[0] = *reinterpret_cast<const s16x4*>(&Vsb[(32 + l31) * 64 + g0]);
    a1.h[1] = *reinterpret_cast<const s16x4*>(&Vsb[(32 + l31) * 64 + g1]);
    o0 = __builtin_amdgcn_mfma_f32_32x32x16_bf16(a0.v, paf[ks], o0, 0, 0, 0);
    o1 = __builtin_amdgcn_mfma_f32_32x32x16_bf16(a1.v, paf[ks], o1, 0, 0, 0);
  }
  __builtin_amdgcn_s_setprio(0);
}

// block = (qp, h, b); strips qtA = qp, qtB = 15-qp -> uniform 34 tile-units/block.
__global__ __launch_bounds__(256) void attn2(const short* __restrict__ Q,
                                             const short* __restrict__ K,
                                             const short* __restrict__ VT,
                                             short* __restrict__ O) {
  constexpr int S = 2048, H = 32;
  const int qp = blockIdx.x, h = blockIdx.y, b = blockIdx.z;
  const int tid = threadIdx.x, lane = tid & 63, wid = tid >> 6;
  const int l31 = lane & 31, hi = lane >> 5;
  const int kvh = h >> 2;
  const int bk = b * 8 + kvh;
  const int qtA = qp, qtB = 15 - qp;
  const int q0A = qtA * 128 + wid * 32, q0B = qtB * 128 + wid * 32;
  const int qrowA = q0A + l31, qrowB = q0B + l31;

  __shared__ short Ks[2][4096];
  __shared__ short Vs[2][4096];

  bf16x8 qfA[4], qfB[4];
  {
    const size_t qa = ((size_t)(b * S + qrowA) * H + h) * 64;
    const size_t qb = ((size_t)(b * S + qrowB) * H + h) * 64;
    #pragma unroll
    for (int ds = 0; ds < 4; ++ds) {
      qfA[ds] = *reinterpret_cast<const bf16x8*>(&Q[qa + ds * 16 + hi * 8]);
      qfB[ds] = *reinterpret_cast<const bf16x8*>(&Q[qb + ds * 16 + hi * 8]);
    }
  }

  f32x16 oA0 = {}, oA1 = {}, oB0 = {}, oB1 = {};
  float mA = -1e30f, lA = 0.f, mB = -1e30f, lB = 0.f;

  const int njt = 2 * qtB + 2;
  const size_t kroot = ((size_t)b * S * 8 + kvh) * 64;  // row stride 512
  const size_t vroot = (size_t)bk * 64 * S;

  #pragma unroll
  for (int i = 0; i < 2; ++i) {
    const int c = i * 256 + tid, r = c >> 3, ch = c & 7;
    const int cs8 = (ch ^ (r & 7)) * 8;
    gload16(&K[kroot + (size_t)r * 512 + cs8], &Ks[0][c * 8]);
    gload16(&VT[vroot + (size_t)r * S + cs8], &Vs[0][c * 8]);
  }
  __syncthreads();

  int cur = 0;
  for (int j = 0; j < njt; ++j) {
    if (j + 1 < njt) {
      #pragma unroll
      for (int i = 0; i < 2; ++i) {
        const int c = i * 256 + tid, r = c >> 3, ch = c & 7;
        const int cs8 = (ch ^ (r & 7)) * 8;
        gload16(&K[kroot + (size_t)((j + 1) * 64 + r) * 512 + cs8], &Ks[cur ^ 1][c * 8]);
        gload16(&VT[vroot + (size_t)r * S + (j + 1) * 64 + cs8], &Vs[cur ^ 1][c * 8]);
      }
    }
    const int kb = j * 64;
    // strip B (always active until its own diagonal)
    if (kb + 63 <= q0B)
      ptile<false>(Ks[cur], Vs[cur], qfB, kb, qrowB, l31, hi, oB0, oB1, mB, lB);
    else if (kb <= q0B + 31)
      ptile<true>(Ks[cur], Vs[cur], qfB, kb, qrowB, l31, hi, oB0, oB1, mB, lB);
    // strip A
    if (kb + 63 <= q0A)
      ptile<false>(Ks[cur], Vs[cur], qfA, kb, qrowA, l31, hi, oA0, oA1, mA, lA);
    else if (kb <= q0A + 31)
      ptile<true>(Ks[cur], Vs[cur], qfA, kb, qrowA, l31, hi, oA0, oA1, mA, lA);
    __syncthreads();
    cur ^= 1;
  }

  // ---- normalize + store both strips ----
  {
    const float inv = 1.f / lA;
    const size_t obase = ((size_t)(b * S + qrowA) * H + h) * 64;
    #pragma unroll
    for (int g = 0; g < 4; ++g) {
      s16x4 s0v, s1v;
      #pragma unroll
      for (int i = 0; i < 4; ++i) {
        s0v[i] = f2bf(oA0[4 * g + i] * inv);
        s1v[i] = f2bf(oA1[4 * g + i] * inv);
      }
      *reinterpret_cast<s16x4*>(&O[obase + 8 * g + 4 * hi]) = s0v;
      *reinterpret_cast<s16x4*>(&O[obase + 32 + 8 * g + 4 * hi]) = s1v;
    }
  }
  {
    const float inv = 1.f / lB;
    const size_t obase = ((size_t)(b * S + qrowB) * H + h) * 64;
    #pragma unroll
    for (int g = 0; g < 4; ++g) {
      s16x4 s0v, s1v;
      #pragma unroll
      for (int i = 0; i < 4; ++i) {
        s0v[i] = f2bf(oB0[4 * g + i] * inv);
        s1v[i] = f2bf(oB1[4 * g + i] * inv);
      }
      *reinterpret_cast<s16x4*>(&O[obase + 8 * g + 4 * hi]) = s0v;
      *reinterpret_cast<s16x4*>(&O[obase + 32 + 8 * g + 4 * hi]) = s1v;
    }
  }
}

extern "C" void kernel_launch(void* const* d_in, const int* in_sizes, int n_in,
                              void* d_out, int out_size, void* d_ws, size_t ws_size,
                              hipStream_t stream) {
  const float* x  = (const float*)d_in[0];
  const float* fc = (const float*)d_in[1];
  const float* fs = (const float*)d_in[2];
  // d_in[3] = mask (unused; causality applied analytically)
  const float* wq = (const float*)d_in[4];
  const float* wk = (const float*)d_in[5];
  const float* wv = (const float*)d_in[6];
  const float* wo = (const float*)d_in[7];
  float* out = (float*)d_out;

  short* xb  = (short*)d_ws;       // [4096][2048]
  short* wqT = xb  + 8388608;      // [2048][2048]
  short* wkT = wqT + 4194304;      // [512][2048]
  short* wvT = wkT + 1048576;      // [512][2048]
  short* woT = wvT + 1048576;      // [2048][2048]
  short* Qb  = woT + 4194304;      // [b,s,32,64]
  short* Kb  = Qb  + 8388608;      // [b,s,8,64]
  short* Vb  = Kb  + 2097152;      // [b,s,8,64]
  short* attb = xb;                // alias: x dead after V GEMM
  short* VTb  = wqT;               // alias: wqT dead after Q GEMM; [bk][64][2048]

  cvt_kernel<<<2048, 256, 0, stream>>>(x, xb, 2097152);
  cvtT_kernel<<<dim3(64, 64), 256, 0, stream>>>(wq, wqT, 2048, 2048);
  cvtT_kernel<<<dim3(64, 16), 256, 0, stream>>>(wk, wkT, 2048, 512);
  cvtT_kernel<<<dim3(64, 16), 256, 0, stream>>>(wv, wvT, 2048, 512);
  cvtT_kernel<<<dim3(64, 64), 256, 0, stream>>>(wo, woT, 2048, 2048);

  gemm_tn<0><<<dim3(32, 16), 256, 0, stream>>>(xb, wqT, Qb, 4096, 2048, 2048);
  gemm_tn<0><<<dim3(32, 4),  256, 0, stream>>>(xb, wkT, Kb, 4096, 512,  2048);
  gemm_tn<0><<<dim3(32, 4),  256, 0, stream>>>(xb, wvT, Vb, 4096, 512,  2048);

  rope8<8><<<4096, 256, 0, stream>>>(Qb, fc, fs, 1048576);
  rope8<6><<<1024, 256, 0, stream>>>(Kb, fc, fs, 262144);

  vtrans<<<dim3(64, 2, 16), 256, 0, stream>>>(Vb, VTb);

  attn2<<<dim3(8, 32, 2), 256, 0, stream>>>(Qb, Kb, VTb, attb);

  gemm_tn<1><<<dim3(32, 16), 256, 0, stream>>>(attb, woT, out, 4096, 2048, 2048);
}

// Round 6
// 310.711 us; speedup vs baseline: 2.6856x; 1.2085x over previous
//
#include <hip/hip_runtime.h>
#include <hip/hip_bf16.h>

typedef __bf16 bf16x8 __attribute__((ext_vector_type(8)));
typedef float f32x4 __attribute__((ext_vector_type(4)));
typedef float f32x16 __attribute__((ext_vector_type(16)));
typedef short s16x4 __attribute__((ext_vector_type(4)));
typedef short s16x8 __attribute__((ext_vector_type(8)));

__device__ __forceinline__ short f2bf(float f) {
  union { __bf16 h; short s; } p; p.h = (__bf16)f; return p.s;
}
__device__ __forceinline__ float bf2f(short s) {
  union { unsigned u; float f; } v; v.u = ((unsigned)(unsigned short)s) << 16;
  return v.f;
}
__device__ __forceinline__ void gload16(const void* g, void* l) {
  __builtin_amdgcn_global_load_lds(
      (const __attribute__((address_space(1))) unsigned*)g,
      (__attribute__((address_space(3))) unsigned*)l, 16, 0, 0);
}
__device__ __forceinline__ unsigned pack2(float lo, float hi) {
  union { __bf16 h[2]; unsigned u; } p;
  p.h[0] = (__bf16)lo; p.h[1] = (__bf16)hi;   // v_cvt_pk_bf16_f32
  return p.u;
}
__device__ __forceinline__ float vmax16(const f32x16& v) {
  const float a0 = fmaxf(v[0], v[1]), a1 = fmaxf(v[2], v[3]);
  const float a2 = fmaxf(v[4], v[5]), a3 = fmaxf(v[6], v[7]);
  const float a4 = fmaxf(v[8], v[9]), a5 = fmaxf(v[10], v[11]);
  const float a6 = fmaxf(v[12], v[13]), a7 = fmaxf(v[14], v[15]);
  const float b0 = fmaxf(a0, a1), b1 = fmaxf(a2, a3);
  const float b2 = fmaxf(a4, a5), b3 = fmaxf(a6, a7);
  return fmaxf(fmaxf(b0, b1), fmaxf(b2, b3));
}
__device__ __forceinline__ float vsum16(const f32x16& v) {
  const float a0 = v[0] + v[1], a1 = v[2] + v[3], a2 = v[4] + v[5], a3 = v[6] + v[7];
  const float a4 = v[8] + v[9], a5 = v[10] + v[11], a6 = v[12] + v[13], a7 = v[14] + v[15];
  return ((a0 + a1) + (a2 + a3)) + ((a4 + a5) + (a6 + a7));
}

constexpr float KSC = 0.18033688f;  // 1/sqrt(64) * log2(e) — folded into Q at RoPE

// ---------------- fp32 -> bf16 convert ----------------
__global__ void cvt_kernel(const float* __restrict__ in, short* __restrict__ out, int n4) {
  for (int i = blockIdx.x * blockDim.x + threadIdx.x; i < n4; i += gridDim.x * blockDim.x) {
    const float4 v = reinterpret_cast<const float4*>(in)[i];
    s16x4 o;
    o[0] = f2bf(v.x); o[1] = f2bf(v.y); o[2] = f2bf(v.z); o[3] = f2bf(v.w);
    reinterpret_cast<s16x4*>(out)[i] = o;
  }
}

// ------------- fp32 [K][N] -> bf16 transposed [N][K] -------------
__global__ __launch_bounds__(256) void cvtT_kernel(const float* __restrict__ W,
                                                   short* __restrict__ WT, int K, int N) {
  __shared__ float T[32][33];
  const int k0 = blockIdx.x * 32, n0 = blockIdx.y * 32;
  const int r = threadIdx.x >> 5, c = threadIdx.x & 31;
  #pragma unroll
  for (int q = 0; q < 4; ++q) T[r + q * 8][c] = W[(size_t)(k0 + r + q * 8) * N + n0 + c];
  __syncthreads();
  #pragma unroll
  for (int q = 0; q < 4; ++q) WT[(size_t)(n0 + r + q * 8) * K + k0 + c] = f2bf(T[c][r + q * 8]);
}

// ------------- bf16 V [b,s,8,64] -> VT [b*8+kvh][d][s] -------------
__global__ __launch_bounds__(256) void vtrans(const short* __restrict__ Vin,
                                              short* __restrict__ VT) {
  __shared__ short T[32][33];
  const int st0 = blockIdx.x * 32;
  const int d0 = blockIdx.y * 32;
  const int bk = blockIdx.z;
  const int b = bk >> 3, kvh = bk & 7;
  const int r = threadIdx.x >> 5, c = threadIdx.x & 31;
  #pragma unroll
  for (int q = 0; q < 4; ++q)
    T[r + q * 8][c] = Vin[((size_t)(b * 2048 + st0 + r + q * 8) * 8 + kvh) * 64 + d0 + c];
  __syncthreads();
  #pragma unroll
  for (int q = 0; q < 4; ++q)
    VT[((size_t)bk * 64 + d0 + r + q * 8) * 2048 + st0 + c] = T[c][r + q * 8];
}

// ---------------- RoPE in-place, optional output scale ----------------
template <int SHIFT>
__global__ void rope8(short* __restrict__ X, const float* __restrict__ cosT,
                      const float* __restrict__ sinT, int n, float scale) {
  const int i = blockIdx.x * blockDim.x + threadIdx.x;
  if (i >= n) return;
  const int s = (i >> SHIFT) & 2047;
  const int p0 = (i & 7) * 4;
  s16x8 v = *reinterpret_cast<const s16x8*>(&X[(size_t)i * 8]);
  #pragma unroll
  for (int jj = 0; jj < 4; ++jj) {
    const float c = cosT[s * 32 + p0 + jj];
    const float sn = sinT[s * 32 + p0 + jj];
    const float e = bf2f(v[2 * jj]), o = bf2f(v[2 * jj + 1]);
    v[2 * jj] = f2bf((e * c - o * sn) * scale);
    v[2 * jj + 1] = f2bf((e * sn + o * c) * scale);
  }
  *reinterpret_cast<s16x8*>(&X[(size_t)i * 8]) = v;
}

// ---------------- m97-style bf16 GEMM: A[M,K] @ BT[N,K]^T, 128x128, BK=64 ----------------
template <int EPI>
__global__ __launch_bounds__(256) void gemm_tn(const short* __restrict__ A,
                                               const short* __restrict__ BT,
                                               void* __restrict__ C0,
                                               int M, int N, int K) {
  __shared__ short As[128 * 64];
  __shared__ short Bs[128 * 64];
  const int tid = threadIdx.x, lane = tid & 63, wid = tid >> 6;
  const int row0 = blockIdx.x * 128, col0 = blockIdx.y * 128;
  const int wr = (wid >> 1) * 64, wc = (wid & 1) * 64;
  const int lr = lane & 15, lk = (lane >> 4) * 8;
  f32x4 acc[4][4] = {};

  for (int k0 = 0; k0 < K; k0 += 64) {
    #pragma unroll
    for (int i = 0; i < 4; ++i) {
      const int c = i * 256 + tid, r = c >> 3, ch = (c & 7) * 8;
      gload16(&A[(size_t)(row0 + r) * K + k0 + ch], &As[r * 64 + ch]);
      gload16(&BT[(size_t)(col0 + r) * K + k0 + ch], &Bs[r * 64 + ch]);
    }
    __syncthreads();
    #pragma unroll
    for (int kk = 0; kk < 64; kk += 32) {
      bf16x8 af[4], bfr[4];
      #pragma unroll
      for (int m = 0; m < 4; ++m)
        af[m] = *reinterpret_cast<const bf16x8*>(&As[(wr + m * 16 + lr) * 64 + kk + lk]);
      #pragma unroll
      for (int n = 0; n < 4; ++n)
        bfr[n] = *reinterpret_cast<const bf16x8*>(&Bs[(wc + n * 16 + lr) * 64 + kk + lk]);
      #pragma unroll
      for (int m = 0; m < 4; ++m)
        #pragma unroll
        for (int n = 0; n < 4; ++n)
          acc[m][n] = __builtin_amdgcn_mfma_f32_16x16x32_bf16(af[m], bfr[n], acc[m][n], 0, 0, 0);
    }
    __syncthreads();
  }

  const int lc = lane & 15, lr4 = (lane >> 4) * 4;
  #pragma unroll
  for (int m = 0; m < 4; ++m)
    #pragma unroll
    for (int n = 0; n < 4; ++n)
      #pragma unroll
      for (int i = 0; i < 4; ++i) {
        const int row = row0 + wr + m * 16 + lr4 + i;
        const int col = col0 + wc + n * 16 + lc;
        if constexpr (EPI == 0) ((short*)C0)[(size_t)row * N + col] = f2bf(acc[m][n][i]);
        else                    ((float*)C0)[(size_t)row * N + col] = acc[m][n][i];
      }
}

// ---------------- causal GQA flash attention ----------------
// Swapped both ways (verified R4/R5): QK^T = mfma(K,Q), PV = mfma(VT,P); stats lane-local.
// Scores arrive in log2 domain (KSC folded into Q). Block = 8 waves = 4 heads x 2 rowhalves
// sharing one K/V staging; each wave owns paired strips A (low) / B (high).

// single-strip tile
template <bool MASKED>
__device__ __forceinline__ void ptile(const short* __restrict__ Ksb,
                                      const short* __restrict__ Vsb,
                                      const bf16x8 qf[4], int kb, int qrow,
                                      int l31, int hi,
                                      f32x16& o0, f32x16& o1, float& m_r, float& l_r) {
  f32x16 sa0 = {}, sa1 = {};
  __builtin_amdgcn_s_setprio(1);
  #pragma unroll
  for (int ds = 0; ds < 4; ++ds) {
    const int c0 = ((ds * 2 + hi) ^ (l31 & 7)) * 8;
    const bf16x8 kf0 = *reinterpret_cast<const bf16x8*>(&Ksb[l31 * 64 + c0]);
    const bf16x8 kf1 = *reinterpret_cast<const bf16x8*>(&Ksb[(32 + l31) * 64 + c0]);
    sa0 = __builtin_amdgcn_mfma_f32_32x32x16_bf16(kf0, qf[ds], sa0, 0, 0, 0);
    sa1 = __builtin_amdgcn_mfma_f32_32x32x16_bf16(kf1, qf[ds], sa1, 0, 0, 0);
  }
  __builtin_amdgcn_s_setprio(0);
  if (MASKED) {
    #pragma unroll
    for (int r = 0; r < 16; ++r) {
      const int kk = kb + (r & 3) + 8 * (r >> 2) + 4 * hi;
      if (kk > qrow) sa0[r] = -1e30f;
      if (kk + 32 > qrow) sa1[r] = -1e30f;
    }
  }
  float mx = fmaxf(vmax16(sa0), vmax16(sa1));
  mx = fmaxf(mx, __shfl_xor(mx, 32, 64));
  if (!__all(mx <= m_r + 8.0f)) {
    const float mn = fmaxf(m_r, mx);
    const float sc = exp2f(m_r - mn);
    #pragma unroll
    for (int r = 0; r < 16; ++r) { o0[r] *= sc; o1[r] *= sc; }
    l_r *= sc;
    m_r = mn;
  }
  #pragma unroll
  for (int r = 0; r < 16; ++r) {
    sa0[r] = exp2f(sa0[r] - m_r);
    sa1[r] = exp2f(sa1[r] - m_r);
  }
  float ls = vsum16(sa0) + vsum16(sa1);
  ls += __shfl_xor(ls, 32, 64);
  l_r += ls;
  bf16x8 paf[4];
  #pragma unroll
  for (int ks = 0; ks < 4; ++ks) {
    union { unsigned w[4]; bf16x8 v; } u;
    #pragma unroll
    for (int w2 = 0; w2 < 4; ++w2) {
      const int rbase = (ks & 1) * 8 + w2 * 2;
      if (ks < 2) u.w[w2] = pack2(sa0[rbase], sa0[rbase + 1]);
      else        u.w[w2] = pack2(sa1[rbase], sa1[rbase + 1]);
    }
    paf[ks] = u.v;
  }
  __builtin_amdgcn_s_setprio(1);
  #pragma unroll
  for (int ks = 0; ks < 4; ++ks) {
    const int g0 = ((2 * ks) ^ (l31 & 7)) * 8 + hi * 4;
    const int g1 = ((2 * ks + 1) ^ (l31 & 7)) * 8 + hi * 4;
    union { s16x4 h2[2]; bf16x8 v; } a0, a1;
    a0.h2[0] = *reinterpret_cast<const s16x4*>(&Vsb[l31 * 64 + g0]);
    a0.h2[1] = *reinterpret_cast<const s16x4*>(&Vsb[l31 * 64 + g1]);
    a1.h2[0] = *reinterpret_cast<const s16x4*>(&Vsb[(32 + l31) * 64 + g0]);
    a1.h2[1] = *reinterpret_cast<const s16x4*>(&Vsb[(32 + l31) * 64 + g1]);
    o0 = __builtin_amdgcn_mfma_f32_32x32x16_bf16(a0.v, paf[ks], o0, 0, 0, 0);
    o1 = __builtin_amdgcn_mfma_f32_32x32x16_bf16(a1.v, paf[ks], o1, 0, 0, 0);
  }
  __builtin_amdgcn_s_setprio(0);
}

// fused dual-strip tile: shared K/V fragments, two independent softmax chains (ILP).
// B is always unmasked when A is active (q0B >= q0A + 1024 > kb+63).
template <bool MA>
__device__ __forceinline__ void ptile2(const short* __restrict__ Ksb,
                                       const short* __restrict__ Vsb,
                                       const bf16x8 qfA[4], const bf16x8 qfB[4],
                                       int kb, int qrowA, int l31, int hi,
                                       f32x16& oA0, f32x16& oA1, f32x16& oB0, f32x16& oB1,
                                       float& mA, float& lA, float& mB, float& lB) {
  f32x16 a0 = {}, a1 = {}, b0 = {}, b1 = {};
  __builtin_amdgcn_s_setprio(1);
  #pragma unroll
  for (int ds = 0; ds < 4; ++ds) {
    const int c0 = ((ds * 2 + hi) ^ (l31 & 7)) * 8;
    const bf16x8 kf0 = *reinterpret_cast<const bf16x8*>(&Ksb[l31 * 64 + c0]);
    const bf16x8 kf1 = *reinterpret_cast<const bf16x8*>(&Ksb[(32 + l31) * 64 + c0]);
    a0 = __builtin_amdgcn_mfma_f32_32x32x16_bf16(kf0, qfA[ds], a0, 0, 0, 0);
    b0 = __builtin_amdgcn_mfma_f32_32x32x16_bf16(kf0, qfB[ds], b0, 0, 0, 0);
    a1 = __builtin_amdgcn_mfma_f32_32x32x16_bf16(kf1, qfA[ds], a1, 0, 0, 0);
    b1 = __builtin_amdgcn_mfma_f32_32x32x16_bf16(kf1, qfB[ds], b1, 0, 0, 0);
  }
  __builtin_amdgcn_s_setprio(0);
  if (MA) {
    #pragma unroll
    for (int r = 0; r < 16; ++r) {
      const int kk = kb + (r & 3) + 8 * (r >> 2) + 4 * hi;
      if (kk > qrowA) a0[r] = -1e30f;
      if (kk + 32 > qrowA) a1[r] = -1e30f;
    }
  }
  float mxA = fmaxf(vmax16(a0), vmax16(a1));
  float mxB = fmaxf(vmax16(b0), vmax16(b1));
  mxA = fmaxf(mxA, __shfl_xor(mxA, 32, 64));
  mxB = fmaxf(mxB, __shfl_xor(mxB, 32, 64));
  if (!__all(mxA <= mA + 8.0f)) {
    const float mn = fmaxf(mA, mxA);
    const float sc = exp2f(mA - mn);
    #pragma unroll
    for (int r = 0; r < 16; ++r) { oA0[r] *= sc; oA1[r] *= sc; }
    lA *= sc; mA = mn;
  }
  if (!__all(mxB <= mB + 8.0f)) {
    const float mn = fmaxf(mB, mxB);
    const float sc = exp2f(mB - mn);
    #pragma unroll
    for (int r = 0; r < 16; ++r) { oB0[r] *= sc; oB1[r] *= sc; }
    lB *= sc; mB = mn;
  }
  #pragma unroll
  for (int r = 0; r < 16; ++r) {
    a0[r] = exp2f(a0[r] - mA);
    b0[r] = exp2f(b0[r] - mB);
    a1[r] = exp2f(a1[r] - mA);
    b1[r] = exp2f(b1[r] - mB);
  }
  float lsA = vsum16(a0) + vsum16(a1);
  float lsB = vsum16(b0) + vsum16(b1);
  lsA += __shfl_xor(lsA, 32, 64);
  lsB += __shfl_xor(lsB, 32, 64);
  lA += lsA; lB += lsB;
  bf16x8 pafA[4], pafB[4];
  #pragma unroll
  for (int ks = 0; ks < 4; ++ks) {
    union { unsigned w[4]; bf16x8 v; } ua, ub;
    #pragma unroll
    for (int w2 = 0; w2 < 4; ++w2) {
      const int rbase = (ks & 1) * 8 + w2 * 2;
      if (ks < 2) { ua.w[w2] = pack2(a0[rbase], a0[rbase + 1]);
                    ub.w[w2] = pack2(b0[rbase], b0[rbase + 1]); }
      else        { ua.w[w2] = pack2(a1[rbase], a1[rbase + 1]);
                    ub.w[w2] = pack2(b1[rbase], b1[rbase + 1]); }
    }
    pafA[ks] = ua.v; pafB[ks] = ub.v;
  }
  __builtin_amdgcn_s_setprio(1);
  #pragma unroll
  for (int ks = 0; ks < 4; ++ks) {
    const int g0 = ((2 * ks) ^ (l31 & 7)) * 8 + hi * 4;
    const int g1 = ((2 * ks + 1) ^ (l31 & 7)) * 8 + hi * 4;
    union { s16x4 h2[2]; bf16x8 v; } v0, v1;
    v0.h2[0] = *reinterpret_cast<const s16x4*>(&Vsb[l31 * 64 + g0]);
    v0.h2[1] = *reinterpret_cast<const s16x4*>(&Vsb[l31 * 64 + g1]);
    v1.h2[0] = *reinterpret_cast<const s16x4*>(&Vsb[(32 + l31) * 64 + g0]);
    v1.h2[1] = *reinterpret_cast<const s16x4*>(&Vsb[(32 + l31) * 64 + g1]);
    oA0 = __builtin_amdgcn_mfma_f32_32x32x16_bf16(v0.v, pafA[ks], oA0, 0, 0, 0);
    oB0 = __builtin_amdgcn_mfma_f32_32x32x16_bf16(v0.v, pafB[ks], oB0, 0, 0, 0);
    oA1 = __builtin_amdgcn_mfma_f32_32x32x16_bf16(v1.v, pafA[ks], oA1, 0, 0, 0);
    oB1 = __builtin_amdgcn_mfma_f32_32x32x16_bf16(v1.v, pafB[ks], oB1, 0, 0, 0);
  }
  __builtin_amdgcn_s_setprio(0);
}

// block = (pair, kvh, b): 8 waves = 4 heads x 2 rowhalves; strips qpA=pair, qpB=31-pair (64 rows).
__global__ __launch_bounds__(512, 2) void attn3(const short* __restrict__ Q,
                                                const short* __restrict__ K,
                                                const short* __restrict__ VT,
                                                short* __restrict__ O) {
  constexpr int S = 2048, H = 32;
  const int pair = blockIdx.x, kvh = blockIdx.y, b = blockIdx.z;
  const int tid = threadIdx.x, lane = tid & 63, wid = tid >> 6;
  const int hg = wid & 3, rowhalf = wid >> 2;
  const int h = kvh * 4 + hg;
  const int l31 = lane & 31, hi = lane >> 5;
  const int qpA = pair, qpB = 31 - pair;
  const int q0A = qpA * 64 + rowhalf * 32, q0B = qpB * 64 + rowhalf * 32;
  const int qrowA = q0A + l31, qrowB = q0B + l31;
  const int bk = b * 8 + kvh;

  __shared__ short Ks[2][4096];
  __shared__ short Vs[2][4096];

  bf16x8 qfA[4], qfB[4];
  {
    const size_t qa = ((size_t)(b * S + qrowA) * H + h) * 64;
    const size_t qb = ((size_t)(b * S + qrowB) * H + h) * 64;
    #pragma unroll
    for (int ds = 0; ds < 4; ++ds) {
      qfA[ds] = *reinterpret_cast<const bf16x8*>(&Q[qa + ds * 16 + hi * 8]);
      qfB[ds] = *reinterpret_cast<const bf16x8*>(&Q[qb + ds * 16 + hi * 8]);
    }
  }

  f32x16 oA0 = {}, oA1 = {}, oB0 = {}, oB1 = {};
  float mA = -1e30f, lA = 0.f, mB = -1e30f, lB = 0.f;

  const int njt = qpB + 1;
  const size_t kroot = ((size_t)b * S * 8 + kvh) * 64;  // row stride 512
  const size_t vroot = (size_t)bk * 64 * S;

  const int sr = tid >> 3, sch = tid & 7;
  const int cs8 = (sch ^ (sr & 7)) * 8;
  gload16(&K[kroot + (size_t)sr * 512 + cs8], &Ks[0][tid * 8]);
  gload16(&VT[vroot + (size_t)sr * S + cs8], &Vs[0][tid * 8]);
  __syncthreads();

  int cur = 0;
  for (int j = 0; j < njt; ++j) {
    if (j + 1 < njt) {
      gload16(&K[kroot + (size_t)((j + 1) * 64 + sr) * 512 + cs8], &Ks[cur ^ 1][tid * 8]);
      gload16(&VT[vroot + (size_t)sr * S + (j + 1) * 64 + cs8], &Vs[cur ^ 1][tid * 8]);
    }
    const int kb = j * 64;
    if (kb <= q0A + 31) {
      if (kb + 63 <= q0A)
        ptile2<false>(Ks[cur], Vs[cur], qfA, qfB, kb, qrowA, l31, hi,
                      oA0, oA1, oB0, oB1, mA, lA, mB, lB);
      else
        ptile2<true>(Ks[cur], Vs[cur], qfA, qfB, kb, qrowA, l31, hi,
                     oA0, oA1, oB0, oB1, mA, lA, mB, lB);
    } else if (kb <= q0B + 31) {
      if (kb + 63 <= q0B)
        ptile<false>(Ks[cur], Vs[cur], qfB, kb, qrowB, l31, hi, oB0, oB1, mB, lB);
      else
        ptile<true>(Ks[cur], Vs[cur], qfB, kb, qrowB, l31, hi, oB0, oB1, mB, lB);
    }
    __syncthreads();
    cur ^= 1;
  }

  {
    const float inv = 1.f / lA;
    const size_t obase = ((size_t)(b * S + qrowA) * H + h) * 64;
    #pragma unroll
    for (int g = 0; g < 4; ++g) {
      s16x4 s0v, s1v;
      #pragma unroll
      for (int i = 0; i < 4; ++i) {
        s0v[i] = f2bf(oA0[4 * g + i] * inv);
        s1v[i] = f2bf(oA1[4 * g + i] * inv);
      }
      *reinterpret_cast<s16x4*>(&O[obase + 8 * g + 4 * hi]) = s0v;
      *reinterpret_cast<s16x4*>(&O[obase + 32 + 8 * g + 4 * hi]) = s1v;
    }
  }
  {
    const float inv = 1.f / lB;
    const size_t obase = ((size_t)(b * S + qrowB) * H + h) * 64;
    #pragma unroll
    for (int g = 0; g < 4; ++g) {
      s16x4 s0v, s1v;
      #pragma unroll
      for (int i = 0; i < 4; ++i) {
        s0v[i] = f2bf(oB0[4 * g + i] * inv);
        s1v[i] = f2bf(oB1[4 * g + i] * inv);
      }
      *reinterpret_cast<s16x4*>(&O[obase + 8 * g + 4 * hi]) = s0v;
      *reinterpret_cast<s16x4*>(&O[obase + 32 + 8 * g + 4 * hi]) = s1v;
    }
  }
}

extern "C" void kernel_launch(void* const* d_in, const int* in_sizes, int n_in,
                              void* d_out, int out_size, void* d_ws, size_t ws_size,
                              hipStream_t stream) {
  const float* x  = (const float*)d_in[0];
  const float* fc = (const float*)d_in[1];
  const float* fs = (const float*)d_in[2];
  // d_in[3] = mask (unused; causality applied analytically)
  const float* wq = (const float*)d_in[4];
  const float* wk = (const float*)d_in[5];
  const float* wv = (const float*)d_in[6];
  const float* wo = (const float*)d_in[7];
  float* out = (float*)d_out;

  short* xb  = (short*)d_ws;       // [4096][2048]
  short* wqT = xb  + 8388608;      // [2048][2048]
  short* wkT = wqT + 4194304;      // [512][2048]
  short* wvT = wkT + 1048576;      // [512][2048]
  short* woT = wvT + 1048576;      // [2048][2048]
  short* Qb  = woT + 4194304;      // [b,s,32,64]
  short* Kb  = Qb  + 8388608;      // [b,s,8,64]
  short* Vb  = Kb  + 2097152;      // [b,s,8,64]
  short* attb = xb;                // alias: x dead after V GEMM
  short* VTb  = wqT;               // alias: wqT dead after Q GEMM; [bk][64][2048]

  cvt_kernel<<<2048, 256, 0, stream>>>(x, xb, 2097152);
  cvtT_kernel<<<dim3(64, 64), 256, 0, stream>>>(wq, wqT, 2048, 2048);
  cvtT_kernel<<<dim3(64, 16), 256, 0, stream>>>(wk, wkT, 2048, 512);
  cvtT_kernel<<<dim3(64, 16), 256, 0, stream>>>(wv, wvT, 2048, 512);
  cvtT_kernel<<<dim3(64, 64), 256, 0, stream>>>(wo, woT, 2048, 2048);

  gemm_tn<0><<<dim3(32, 16), 256, 0, stream>>>(xb, wqT, Qb, 4096, 2048, 2048);
  gemm_tn<0><<<dim3(32, 4),  256, 0, stream>>>(xb, wkT, Kb, 4096, 512,  2048);
  gemm_tn<0><<<dim3(32, 4),  256, 0, stream>>>(xb, wvT, Vb, 4096, 512,  2048);

  // Q gets KSC folded in (log2-domain scores); K unscaled
  rope8<8><<<4096, 256, 0, stream>>>(Qb, fc, fs, 1048576, KSC);
  rope8<6><<<1024, 256, 0, stream>>>(Kb, fc, fs, 262144, 1.0f);

  vtrans<<<dim3(64, 2, 16), 256, 0, stream>>>(Vb, VTb);

  attn3<<<dim3(16, 8, 2), 512, 0, stream>>>(Qb, Kb, VTb, attb);

  gemm_tn<1><<<dim3(32, 16), 256, 0, stream>>>(attb, woT, out, 4096, 2048, 2048);
}